// Round 1
// baseline (22.341 us; speedup 1.0000x reference)
//
#include <hip/hip_runtime.h>
#include <math.h>

// out[n,d] = (0.5 - (1/256) * sum_k |tanh(x[n,k]) - tanh(w[d,k])|) * gain[d]
// (straight-through estimator: forward value is the L1 branch only)

#define DIN 256
#define KT 128        // k-tile staged per phase
#define STRIDE 132    // padded float stride per LDS row (132 % 32 == 4 -> conflict-free)
#define TM 32         // output rows per block
#define TN 32         // output cols per block

__device__ __forceinline__ float4 tanh4(float4 v) {
  v.x = tanhf(v.x); v.y = tanhf(v.y); v.z = tanhf(v.z); v.w = tanhf(v.w);
  return v;
}

__global__ void tanh_pre_kernel(const float* __restrict__ x,
                                const float* __restrict__ w,
                                float* __restrict__ xa,
                                float* __restrict__ wa,
                                int nx4, int nw4) {
  int i = blockIdx.x * blockDim.x + threadIdx.x;
  if (i < nx4) {
    float4 v = reinterpret_cast<const float4*>(x)[i];
    reinterpret_cast<float4*>(xa)[i] = tanh4(v);
  } else if (i < nx4 + nw4) {
    int j = i - nx4;
    float4 v = reinterpret_cast<const float4*>(w)[j];
    reinterpret_cast<float4*>(wa)[j] = tanh4(v);
  }
}

// FUSED=true: X/W are raw inputs, tanh applied during LDS staging (ws fallback).
// FUSED=false: X/W are pre-tanh'd activations from d_ws.
template<bool FUSED>
__global__ __launch_bounds__(256, 2) void l1_main_kernel(
    const float* __restrict__ X,   // (N, 256)
    const float* __restrict__ W,   // (256, 256)
    const float* __restrict__ G,   // (256,)
    float* __restrict__ out) {     // (N, 256)
  __shared__ float xs[TM * STRIDE];
  __shared__ float wsl[TN * STRIDE];

  const int tid  = threadIdx.x;
  const int r0   = blockIdx.x * TM;
  const int c0   = blockIdx.y * TN;

  const int wave = tid >> 6;     // 0..3, each wave owns 8 rows
  const int lane = tid & 63;
  const int lr   = lane >> 4;    // 0..3 row-sublane
  const int lc   = lane & 15;    // 0..15 col-lane

  float acc[2][2] = {{0.f, 0.f}, {0.f, 0.f}};

  for (int kp = 0; kp < DIN; kp += KT) {
    __syncthreads();   // LDS reuse safety across k-phases (no-op cost on phase 0)

    // stage x tile: TM rows x KT floats (KT/4 = 32 float4 per row)
    for (int it = tid; it < TM * (KT / 4); it += 256) {
      int r  = it >> 5;
      int c4 = it & 31;
      float4 v = *reinterpret_cast<const float4*>(X + (size_t)(r0 + r) * DIN + kp + c4 * 4);
      if (FUSED) v = tanh4(v);
      *reinterpret_cast<float4*>(&xs[r * STRIDE + c4 * 4]) = v;
    }
    // stage w tile: TN rows x KT floats
    for (int it = tid; it < TN * (KT / 4); it += 256) {
      int r  = it >> 5;
      int c4 = it & 31;
      float4 v = *reinterpret_cast<const float4*>(W + (size_t)(c0 + r) * DIN + kp + c4 * 4);
      if (FUSED) v = tanh4(v);
      *reinterpret_cast<float4*>(&wsl[r * STRIDE + c4 * 4]) = v;
    }
    __syncthreads();

    const float* xb = &xs[(8 * wave + lr) * STRIDE];
    const float* wb = &wsl[lc * STRIDE];

#pragma unroll
    for (int k = 0; k < KT; k += 4) {
      float4 x0 = *reinterpret_cast<const float4*>(xb + k);
      float4 x1 = *reinterpret_cast<const float4*>(xb + 4 * STRIDE + k);
      float4 w0 = *reinterpret_cast<const float4*>(wb + k);
      float4 w1 = *reinterpret_cast<const float4*>(wb + 16 * STRIDE + k);
      // tree-sum: only ONE dependent add into each acc per k-step
      acc[0][0] += (fabsf(x0.x - w0.x) + fabsf(x0.y - w0.y)) +
                   (fabsf(x0.z - w0.z) + fabsf(x0.w - w0.w));
      acc[0][1] += (fabsf(x0.x - w1.x) + fabsf(x0.y - w1.y)) +
                   (fabsf(x0.z - w1.z) + fabsf(x0.w - w1.w));
      acc[1][0] += (fabsf(x1.x - w0.x) + fabsf(x1.y - w0.y)) +
                   (fabsf(x1.z - w0.z) + fabsf(x1.w - w0.w));
      acc[1][1] += (fabsf(x1.x - w1.x) + fabsf(x1.y - w1.y)) +
                   (fabsf(x1.z - w1.z) + fabsf(x1.w - w1.w));
    }
  }

  const float inv = 1.0f / DIN;
#pragma unroll
  for (int j = 0; j < 2; ++j) {
    int C = c0 + lc + 16 * j;
    float g = G[C];
#pragma unroll
    for (int i = 0; i < 2; ++i) {
      int R = r0 + 8 * wave + lr + 4 * i;
      out[(size_t)R * 256 + C] = (0.5f - acc[i][j] * inv) * g;
    }
  }
}

extern "C" void kernel_launch(void* const* d_in, const int* in_sizes, int n_in,
                              void* d_out, int out_size, void* d_ws, size_t ws_size,
                              hipStream_t stream) {
  const float* x = (const float*)d_in[0];   // (2,1024,256) f32
  const float* w = (const float*)d_in[1];   // (256,256) f32
  const float* g = (const float*)d_in[2];   // (1,256,1) f32
  float* out = (float*)d_out;               // (2,1024,256) f32

  const int N    = in_sizes[0] / DIN;       // 2048
  const int Dout = 256;

  dim3 grid(N / TM, Dout / TN);             // (64, 8) = 512 blocks

  const size_t need = ((size_t)N * DIN + (size_t)Dout * DIN) * sizeof(float);
  if (ws_size >= need) {
    float* xa = (float*)d_ws;
    float* wa = xa + (size_t)N * DIN;
    int nx4 = N * DIN / 4;                  // 131072
    int nw4 = Dout * DIN / 4;               // 16384
    int total = nx4 + nw4;
    tanh_pre_kernel<<<(total + 255) / 256, 256, 0, stream>>>(x, w, xa, wa, nx4, nw4);
    l1_main_kernel<false><<<grid, 256, 0, stream>>>(xa, wa, g, out);
  } else {
    // fallback: tanh fused into staging (recomputes tanh per tile)
    l1_main_kernel<true><<<grid, 256, 0, stream>>>(x, w, g, out);
  }
}

// Round 3
// 22.248 us; speedup vs baseline: 1.0042x; 1.0042x over previous
//
#include <hip/hip_runtime.h>
#include <math.h>

// out[n,d] = (0.5 - (1/256) * sum_k |tanh(x[n,k]) - tanh(w[d,k])|) * gain[d]
// Straight-through estimator: forward value is the L1 branch only.
//
// Strategy: pre-kernel computes tanh(x), tanh(w) -> fp16 in d_ws.
// Main kernel: block = 8 x-rows x 128 w-cols. w half-tile (128x256 fp16) in
// LDS (stride 264 halves = 528B = 4 dwords mod 32 -> optimal bank pattern for
// lane-per-row ds_read_b128). x rows broadcast from LDS. Inner op: packed fp16
// sub + packed abs (v_and) + v_dot2_f32_f16 accumulate = 3 VALU / 2 elements.

typedef _Float16 half2_t __attribute__((ext_vector_type(2)));
typedef _Float16 half8_t __attribute__((ext_vector_type(8)));

#define DIN 256
#define BM 8        // x-rows per block
#define CH 128      // w-cols per block
#define WSTR 264    // LDS row stride in halves (528 B)

// x2,w2 are packed half2 pairs carried as dwords
__device__ __forceinline__ float absdot(unsigned x2, unsigned w2, float acc) {
  half2_t d = __builtin_bit_cast(half2_t, x2) - __builtin_bit_cast(half2_t, w2);
  unsigned u = __builtin_bit_cast(unsigned, d) & 0x7FFF7FFFu;   // packed abs
  half2_t ad = __builtin_bit_cast(half2_t, u);
  half2_t one;
  one[0] = (_Float16)1.0f;
  one[1] = (_Float16)1.0f;
#if __has_builtin(__builtin_amdgcn_fdot2)
  return __builtin_amdgcn_fdot2(ad, one, acc, false);  // v_dot2_f32_f16
#else
  return acc + (float)ad[0] + (float)ad[1];
#endif
}

__global__ void tanh_pre(const float* __restrict__ x, const float* __restrict__ w,
                         _Float16* __restrict__ xa, _Float16* __restrict__ wa,
                         int nx8, int nw8) {
  int i = blockIdx.x * blockDim.x + threadIdx.x;
  const float* s;
  _Float16* dp;
  if (i < nx8)            { s = x + (size_t)i * 8; dp = xa + (size_t)i * 8; }
  else if (i < nx8 + nw8) { int j = i - nx8; s = w + (size_t)j * 8; dp = wa + (size_t)j * 8; }
  else return;
  float4 a = *reinterpret_cast<const float4*>(s);
  float4 b = *reinterpret_cast<const float4*>(s + 4);
  half8_t h;
  h[0] = (_Float16)tanhf(a.x); h[1] = (_Float16)tanhf(a.y);
  h[2] = (_Float16)tanhf(a.z); h[3] = (_Float16)tanhf(a.w);
  h[4] = (_Float16)tanhf(b.x); h[5] = (_Float16)tanhf(b.y);
  h[6] = (_Float16)tanhf(b.z); h[7] = (_Float16)tanhf(b.w);
  *reinterpret_cast<half8_t*>(dp) = h;
}

__global__ __launch_bounds__(256, 2) void l1_half_kernel(
    const _Float16* __restrict__ xa,   // (N, 256) fp16
    const _Float16* __restrict__ wa,   // (256, 256) fp16
    const float* __restrict__ G,       // (256,)
    float* __restrict__ out) {         // (N, 256) f32
  __shared__ __align__(16) _Float16 lw[CH * WSTR];  // 67.6 KB
  __shared__ __align__(16) _Float16 lx[BM * WSTR];  // 4.2 KB

  const int tid = threadIdx.x;
  const int r0 = blockIdx.x * BM;
  const int c0 = blockIdx.y * CH;

  // stage w half-tile: CH rows x 256 halves (coalesced 16B chunks)
  for (int c = tid; c < CH * 32; c += 256) {
    int r = c >> 5, sdw = c & 31;
    *reinterpret_cast<half8_t*>(&lw[r * WSTR + sdw * 8]) =
        *reinterpret_cast<const half8_t*>(&wa[(size_t)(c0 + r) * DIN + sdw * 8]);
  }
  // stage x tile: BM rows x 256 halves = 256 chunks, one per thread
  {
    int r = tid >> 5, sdw = tid & 31;
    *reinterpret_cast<half8_t*>(&lx[r * WSTR + sdw * 8]) =
        *reinterpret_cast<const half8_t*>(&xa[(size_t)(r0 + r) * DIN + sdw * 8]);
  }
  __syncthreads();

  const int dl = tid & (CH - 1);      // col within half-tile
  const int rs = (tid >> 7) * 4;      // row base: 0 or 4
  float a0 = 0.f, a1 = 0.f, a2 = 0.f, a3 = 0.f;
  const _Float16* wrow = &lw[dl * WSTR];
  const _Float16* xb   = &lx[rs * WSTR];

#pragma unroll 4
  for (int k = 0; k < DIN; k += 8) {
    uint4 wv = *reinterpret_cast<const uint4*>(wrow + k);
    uint4 x0 = *reinterpret_cast<const uint4*>(xb + k);
    uint4 x1 = *reinterpret_cast<const uint4*>(xb + WSTR + k);
    uint4 x2 = *reinterpret_cast<const uint4*>(xb + 2 * WSTR + k);
    uint4 x3 = *reinterpret_cast<const uint4*>(xb + 3 * WSTR + k);

    a0 = absdot(x0.x, wv.x, a0); a0 = absdot(x0.y, wv.y, a0);
    a0 = absdot(x0.z, wv.z, a0); a0 = absdot(x0.w, wv.w, a0);
    a1 = absdot(x1.x, wv.x, a1); a1 = absdot(x1.y, wv.y, a1);
    a1 = absdot(x1.z, wv.z, a1); a1 = absdot(x1.w, wv.w, a1);
    a2 = absdot(x2.x, wv.x, a2); a2 = absdot(x2.y, wv.y, a2);
    a2 = absdot(x2.z, wv.z, a2); a2 = absdot(x2.w, wv.w, a2);
    a3 = absdot(x3.x, wv.x, a3); a3 = absdot(x3.y, wv.y, a3);
    a3 = absdot(x3.z, wv.z, a3); a3 = absdot(x3.w, wv.w, a3);
  }

  const float inv = 1.0f / DIN;
  const int d = c0 + dl;
  const float g = G[d];
  out[(size_t)(r0 + rs + 0) * 256 + d] = (0.5f - a0 * inv) * g;
  out[(size_t)(r0 + rs + 1) * 256 + d] = (0.5f - a1 * inv) * g;
  out[(size_t)(r0 + rs + 2) * 256 + d] = (0.5f - a2 * inv) * g;
  out[(size_t)(r0 + rs + 3) * 256 + d] = (0.5f - a3 * inv) * g;
}

// ---------------- fallback (ws too small): fused f32 path ----------------
#define KT 128
#define STRIDE 132
#define TM 32
#define TN 32

__device__ __forceinline__ float4 tanh4(float4 v) {
  v.x = tanhf(v.x); v.y = tanhf(v.y); v.z = tanhf(v.z); v.w = tanhf(v.w);
  return v;
}

__global__ __launch_bounds__(256, 2) void l1_f32_fused_kernel(
    const float* __restrict__ X, const float* __restrict__ W,
    const float* __restrict__ G, float* __restrict__ out) {
  __shared__ float xs[TM * STRIDE];
  __shared__ float wsl[TN * STRIDE];
  const int tid = threadIdx.x;
  const int r0 = blockIdx.x * TM;
  const int c0 = blockIdx.y * TN;
  const int wave = tid >> 6;
  const int lane = tid & 63;
  const int lr = lane >> 4;
  const int lc = lane & 15;
  float acc[2][2] = {{0.f, 0.f}, {0.f, 0.f}};
  for (int kp = 0; kp < DIN; kp += KT) {
    __syncthreads();
    for (int it = tid; it < TM * (KT / 4); it += 256) {
      int r = it >> 5, c4 = it & 31;
      float4 v = *reinterpret_cast<const float4*>(X + (size_t)(r0 + r) * DIN + kp + c4 * 4);
      *reinterpret_cast<float4*>(&xs[r * STRIDE + c4 * 4]) = tanh4(v);
    }
    for (int it = tid; it < TN * (KT / 4); it += 256) {
      int r = it >> 5, c4 = it & 31;
      float4 v = *reinterpret_cast<const float4*>(W + (size_t)(c0 + r) * DIN + kp + c4 * 4);
      *reinterpret_cast<float4*>(&wsl[r * STRIDE + c4 * 4]) = tanh4(v);
    }
    __syncthreads();
    const float* xb = &xs[(8 * wave + lr) * STRIDE];
    const float* wb = &wsl[lc * STRIDE];
#pragma unroll
    for (int k = 0; k < KT; k += 4) {
      float4 x0 = *reinterpret_cast<const float4*>(xb + k);
      float4 x1 = *reinterpret_cast<const float4*>(xb + 4 * STRIDE + k);
      float4 w0 = *reinterpret_cast<const float4*>(wb + k);
      float4 w1 = *reinterpret_cast<const float4*>(wb + 16 * STRIDE + k);
      acc[0][0] += (fabsf(x0.x - w0.x) + fabsf(x0.y - w0.y)) + (fabsf(x0.z - w0.z) + fabsf(x0.w - w0.w));
      acc[0][1] += (fabsf(x0.x - w1.x) + fabsf(x0.y - w1.y)) + (fabsf(x0.z - w1.z) + fabsf(x0.w - w1.w));
      acc[1][0] += (fabsf(x1.x - w0.x) + fabsf(x1.y - w0.y)) + (fabsf(x1.z - w0.z) + fabsf(x1.w - w0.w));
      acc[1][1] += (fabsf(x1.x - w1.x) + fabsf(x1.y - w1.y)) + (fabsf(x1.z - w1.z) + fabsf(x1.w - w1.w));
    }
  }
  const float inv = 1.0f / DIN;
#pragma unroll
  for (int j = 0; j < 2; ++j) {
    int C = c0 + lc + 16 * j;
    float g = G[C];
#pragma unroll
    for (int i = 0; i < 2; ++i) {
      int R = r0 + 8 * wave + lr + 4 * i;
      out[(size_t)R * 256 + C] = (0.5f - acc[i][j] * inv) * g;
    }
  }
}

extern "C" void kernel_launch(void* const* d_in, const int* in_sizes, int n_in,
                              void* d_out, int out_size, void* d_ws, size_t ws_size,
                              hipStream_t stream) {
  const float* x = (const float*)d_in[0];   // (2,1024,256) f32
  const float* w = (const float*)d_in[1];   // (256,256) f32
  const float* g = (const float*)d_in[2];   // (1,256,1) f32
  float* out = (float*)d_out;

  const int N = in_sizes[0] / DIN;          // 2048
  const int Dout = 256;
  const size_t nx = (size_t)N * DIN;        // 524288
  const size_t nw = (size_t)Dout * DIN;     // 65536
  const size_t need = (nx + nw) * sizeof(_Float16);

  if (ws_size >= need && (N % BM) == 0) {
    _Float16* xa = (_Float16*)d_ws;
    _Float16* wa = xa + nx;
    int nx8 = (int)(nx / 8), nw8 = (int)(nw / 8);
    int total = nx8 + nw8;                  // 73728
    tanh_pre<<<(total + 255) / 256, 256, 0, stream>>>(x, w, xa, wa, nx8, nw8);
    dim3 grid(N / BM, Dout / CH);           // (256, 2) = 512 blocks
    l1_half_kernel<<<grid, 256, 0, stream>>>(xa, wa, g, out);
  } else {
    dim3 grid(N / TM, Dout / TN);
    l1_f32_fused_kernel<<<grid, 256, 0, stream>>>(x, w, g, out);
  }
}

// Round 4
// 13.357 us; speedup vs baseline: 1.6727x; 1.6657x over previous
//
#include <hip/hip_runtime.h>
#include <math.h>

// out[n,d] = (0.5 - (1/256) * sum_k |tanh(x[n,k]) - tanh(w[d,k])|) * gain[d]
// Straight-through estimator: forward value is the L1 branch only.
//
// Round-4 strategy: tanh values lie in (-1,1) -> quantize to u8 once
// (pre-kernel, step 1/127.5), then the L1 inner product is a pure byte-SAD:
// v_sad_u8 does 4 |a-b| + accumulate in ONE VALU op (0.25 instr/element).
// Main kernel: 32x32 output tile, wave-tile 16x16 (8x8 threads, 2x2/thread),
// full K=256 staged once in LDS (272B row stride -> broadcast reads hit all
// 8 bank groups), one barrier, fully unrolled k-loop with immediate offsets.

#define DIN 256
#define BM 32
#define BN 32
#define XSTR 272   // LDS row stride in bytes (256 + 16)

__device__ __forceinline__ unsigned sad_u8(unsigned a, unsigned b, unsigned acc) {
#if __has_builtin(__builtin_amdgcn_sad_u8)
  return __builtin_amdgcn_sad_u8(a, b, acc);
#else
  unsigned d;
  asm("v_sad_u8 %0, %1, %2, %3" : "=v"(d) : "v"(a), "v"(b), "v"(acc));
  return d;
#endif
}

__global__ void tanh_q8(const float* __restrict__ x, const float* __restrict__ w,
                        unsigned char* __restrict__ xq, unsigned char* __restrict__ wq,
                        int nx16, int nw16) {
  int i = blockIdx.x * blockDim.x + threadIdx.x;
  const float* s;
  unsigned char* dp;
  if (i < nx16)            { s = x + (size_t)i * 16; dp = xq + (size_t)i * 16; }
  else if (i < nx16 + nw16) { int j = i - nx16; s = w + (size_t)j * 16; dp = wq + (size_t)j * 16; }
  else return;
  unsigned pk[4];
#pragma unroll
  for (int q = 0; q < 4; ++q) {
    float4 v = reinterpret_cast<const float4*>(s)[q];
    unsigned b0 = (unsigned)lrintf(tanhf(v.x) * 127.5f + 127.5f);
    unsigned b1 = (unsigned)lrintf(tanhf(v.y) * 127.5f + 127.5f);
    unsigned b2 = (unsigned)lrintf(tanhf(v.z) * 127.5f + 127.5f);
    unsigned b3 = (unsigned)lrintf(tanhf(v.w) * 127.5f + 127.5f);
    pk[q] = b0 | (b1 << 8) | (b2 << 16) | (b3 << 24);
  }
  uint4 o; o.x = pk[0]; o.y = pk[1]; o.z = pk[2]; o.w = pk[3];
  *reinterpret_cast<uint4*>(dp) = o;
}

__global__ __launch_bounds__(256) void l1_sad_kernel(
    const unsigned char* __restrict__ xq,  // (N, 256) u8
    const unsigned char* __restrict__ wq,  // (256, 256) u8
    const float* __restrict__ G,           // (256,)
    float* __restrict__ out) {             // (N, 256) f32
  __shared__ __align__(16) unsigned char xs[BM * XSTR];   // 8.5 KB
  __shared__ __align__(16) unsigned char wsl[BN * XSTR];  // 8.5 KB

  const int tid = threadIdx.x;
  const int r0 = blockIdx.x * BM;
  const int c0 = blockIdx.y * BN;

  // stage both tiles: 512 16B chunks each -> 2 per thread, fully coalesced
#pragma unroll
  for (int p = 0; p < 2; ++p) {
    int id  = tid + p * 256;          // 0..511
    int row = id >> 4;
    int cb  = (id & 15) * 16;
    *reinterpret_cast<uint4*>(&xs[row * XSTR + cb]) =
        *reinterpret_cast<const uint4*>(&xq[(size_t)(r0 + row) * DIN + cb]);
    *reinterpret_cast<uint4*>(&wsl[row * XSTR + cb]) =
        *reinterpret_cast<const uint4*>(&wq[(size_t)(c0 + row) * DIN + cb]);
  }
  __syncthreads();

  const int wave = tid >> 6;            // 0..3 -> 2x2 wave grid of 16x16 tiles
  const int wr = (wave >> 1) * 16;
  const int wc = (wave & 1) * 16;
  const int lane = tid & 63;
  const int tr = lane >> 3;             // 0..7  (x-rows tr, tr+8)
  const int tc = lane & 7;              // 0..7  (w-cols 2tc, 2tc+1)

  const unsigned char* xr0 = &xs[(wr + tr) * XSTR];
  const unsigned char* xr1 = xr0 + 8 * XSTR;
  const unsigned char* wc0 = &wsl[(wc + 2 * tc) * XSTR];
  const unsigned char* wc1 = wc0 + XSTR;

  unsigned a00 = 0, a01 = 0, a10 = 0, a11 = 0;
#pragma unroll
  for (int k = 0; k < 16; ++k) {
    uint4 xv0 = *reinterpret_cast<const uint4*>(xr0 + k * 16);
    uint4 xv1 = *reinterpret_cast<const uint4*>(xr1 + k * 16);
    uint4 wv0 = *reinterpret_cast<const uint4*>(wc0 + k * 16);
    uint4 wv1 = *reinterpret_cast<const uint4*>(wc1 + k * 16);
    a00 = sad_u8(xv0.x, wv0.x, a00); a01 = sad_u8(xv0.x, wv1.x, a01);
    a10 = sad_u8(xv1.x, wv0.x, a10); a11 = sad_u8(xv1.x, wv1.x, a11);
    a00 = sad_u8(xv0.y, wv0.y, a00); a01 = sad_u8(xv0.y, wv1.y, a01);
    a10 = sad_u8(xv1.y, wv0.y, a10); a11 = sad_u8(xv1.y, wv1.y, a11);
    a00 = sad_u8(xv0.z, wv0.z, a00); a01 = sad_u8(xv0.z, wv1.z, a01);
    a10 = sad_u8(xv1.z, wv0.z, a10); a11 = sad_u8(xv1.z, wv1.z, a11);
    a00 = sad_u8(xv0.w, wv0.w, a00); a01 = sad_u8(xv0.w, wv1.w, a01);
    a10 = sad_u8(xv1.w, wv0.w, a10); a11 = sad_u8(xv1.w, wv1.w, a11);
  }

  const float s = 1.0f / (127.5f * 256.0f);
  const int R0 = r0 + wr + tr;
  const int R1 = R0 + 8;
  const int C0 = c0 + wc + 2 * tc;
  const float g0 = G[C0], g1 = G[C0 + 1];
  float2 o0, o1;
  o0.x = (0.5f - a00 * s) * g0; o0.y = (0.5f - a01 * s) * g1;
  o1.x = (0.5f - a10 * s) * g0; o1.y = (0.5f - a11 * s) * g1;
  *reinterpret_cast<float2*>(&out[(size_t)R0 * 256 + C0]) = o0;
  *reinterpret_cast<float2*>(&out[(size_t)R1 * 256 + C0]) = o1;
}

// ---------------- fallback (ws too small): fused f32 path ----------------
#define KT 128
#define STRIDE 132
#define TM 32
#define TN 32

__device__ __forceinline__ float4 tanh4(float4 v) {
  v.x = tanhf(v.x); v.y = tanhf(v.y); v.z = tanhf(v.z); v.w = tanhf(v.w);
  return v;
}

__global__ __launch_bounds__(256, 2) void l1_f32_fused_kernel(
    const float* __restrict__ X, const float* __restrict__ W,
    const float* __restrict__ G, float* __restrict__ out) {
  __shared__ float xs[TM * STRIDE];
  __shared__ float wsl[TN * STRIDE];
  const int tid = threadIdx.x;
  const int r0 = blockIdx.x * TM;
  const int c0 = blockIdx.y * TN;
  const int wave = tid >> 6;
  const int lane = tid & 63;
  const int lr = lane >> 4;
  const int lc = lane & 15;
  float acc[2][2] = {{0.f, 0.f}, {0.f, 0.f}};
  for (int kp = 0; kp < DIN; kp += KT) {
    __syncthreads();
    for (int it = tid; it < TM * (KT / 4); it += 256) {
      int r = it >> 5, c4 = it & 31;
      float4 v = *reinterpret_cast<const float4*>(X + (size_t)(r0 + r) * DIN + kp + c4 * 4);
      *reinterpret_cast<float4*>(&xs[r * STRIDE + c4 * 4]) = tanh4(v);
    }
    for (int it = tid; it < TN * (KT / 4); it += 256) {
      int r = it >> 5, c4 = it & 31;
      float4 v = *reinterpret_cast<const float4*>(W + (size_t)(c0 + r) * DIN + kp + c4 * 4);
      *reinterpret_cast<float4*>(&wsl[r * STRIDE + c4 * 4]) = tanh4(v);
    }
    __syncthreads();
    const float* xb = &xs[(8 * wave + lr) * STRIDE];
    const float* wb = &wsl[lc * STRIDE];
#pragma unroll
    for (int k = 0; k < KT; k += 4) {
      float4 x0 = *reinterpret_cast<const float4*>(xb + k);
      float4 x1 = *reinterpret_cast<const float4*>(xb + 4 * STRIDE + k);
      float4 w0 = *reinterpret_cast<const float4*>(wb + k);
      float4 w1 = *reinterpret_cast<const float4*>(wb + 16 * STRIDE + k);
      acc[0][0] += (fabsf(x0.x - w0.x) + fabsf(x0.y - w0.y)) + (fabsf(x0.z - w0.z) + fabsf(x0.w - w0.w));
      acc[0][1] += (fabsf(x0.x - w1.x) + fabsf(x0.y - w1.y)) + (fabsf(x0.z - w1.z) + fabsf(x0.w - w1.w));
      acc[1][0] += (fabsf(x1.x - w0.x) + fabsf(x1.y - w0.y)) + (fabsf(x1.z - w0.z) + fabsf(x1.w - w0.w));
      acc[1][1] += (fabsf(x1.x - w1.x) + fabsf(x1.y - w1.y)) + (fabsf(x1.z - w1.z) + fabsf(x1.w - w1.w));
    }
  }
  const float inv = 1.0f / DIN;
#pragma unroll
  for (int j = 0; j < 2; ++j) {
    int C = c0 + lc + 16 * j;
    float g = G[C];
#pragma unroll
    for (int i = 0; i < 2; ++i) {
      int R = r0 + 8 * wave + lr + 4 * i;
      out[(size_t)R * 256 + C] = (0.5f - acc[i][j] * inv) * g;
    }
  }
}

extern "C" void kernel_launch(void* const* d_in, const int* in_sizes, int n_in,
                              void* d_out, int out_size, void* d_ws, size_t ws_size,
                              hipStream_t stream) {
  const float* x = (const float*)d_in[0];   // (2,1024,256) f32
  const float* w = (const float*)d_in[1];   // (256,256) f32
  const float* g = (const float*)d_in[2];   // (1,256,1) f32
  float* out = (float*)d_out;

  const int N = in_sizes[0] / DIN;          // 2048
  const int Dout = 256;
  const size_t nx = (size_t)N * DIN;        // 524288
  const size_t nw = (size_t)Dout * DIN;     // 65536
  const size_t need = nx + nw;              // u8 bytes

  if (ws_size >= need && (N % BM) == 0) {
    unsigned char* xqp = (unsigned char*)d_ws;
    unsigned char* wqp = xqp + nx;
    int nx16 = (int)(nx / 16), nw16 = (int)(nw / 16);
    int total = nx16 + nw16;                // 36864
    tanh_q8<<<(total + 255) / 256, 256, 0, stream>>>(x, w, xqp, wqp, nx16, nw16);
    dim3 grid(N / BM, Dout / BN);           // (64, 8) = 512 blocks
    l1_sad_kernel<<<grid, 256, 0, stream>>>(xqp, wqp, g, out);
  } else {
    dim3 grid(N / TM, Dout / TN);
    l1_f32_fused_kernel<<<grid, 256, 0, stream>>>(x, w, g, out);
  }
}

// Round 5
// 12.647 us; speedup vs baseline: 1.7666x; 1.0561x over previous
//
#include <hip/hip_runtime.h>
#include <math.h>

// out[n,d] = (0.5 - (1/256) * sum_k |tanh(x[n,k]) - tanh(w[d,k])|) * gain[d]
// Straight-through estimator: forward value is the L1 branch only.
//
// Round-5: SINGLE fused kernel (dispatch overhead dominates at this size).
// Each block tanh-quantizes its own x-tile and w-tile to u8 in LDS (redundant
// tanh across blocks, but VALU-cheap), then the L1 inner product is byte-SAD:
// v_sad_u8 = 4 |a-b| + accumulate in one VALU op. LDS reads are 8-way
// broadcasts (conflict-free). One barrier total, no workspace.

#define DIN 256
#define BM 32
#define BN 32
#define XSTR 272   // LDS row stride in bytes (256 + 16)

__device__ __forceinline__ unsigned sad_u8(unsigned a, unsigned b, unsigned acc) {
#if __has_builtin(__builtin_amdgcn_sad_u8)
  return __builtin_amdgcn_sad_u8(a, b, acc);
#else
  unsigned d;
  asm("v_sad_u8 %0, %1, %2, %3" : "=v"(d) : "v"(a), "v"(b), "v"(acc));
  return d;
#endif
}

__device__ __forceinline__ float fast_tanh(float x) {
  // clamp so exp never overflows (tanh(9) == 1 - 3e-8, below u8 resolution)
  x = fminf(fmaxf(x, -9.0f), 9.0f);
  float e = __expf(2.0f * x);          // v_exp_f32-based
#if __has_builtin(__builtin_amdgcn_rcpf)
  return (e - 1.0f) * __builtin_amdgcn_rcpf(e + 1.0f);
#else
  return (e - 1.0f) / (e + 1.0f);
#endif
}

__device__ __forceinline__ unsigned quant4(float4 v) {
  unsigned b0 = (unsigned)lrintf(fast_tanh(v.x) * 127.5f + 127.5f);
  unsigned b1 = (unsigned)lrintf(fast_tanh(v.y) * 127.5f + 127.5f);
  unsigned b2 = (unsigned)lrintf(fast_tanh(v.z) * 127.5f + 127.5f);
  unsigned b3 = (unsigned)lrintf(fast_tanh(v.w) * 127.5f + 127.5f);
  return b0 | (b1 << 8) | (b2 << 16) | (b3 << 24);
}

__global__ __launch_bounds__(256) void fused_sad_kernel(
    const float* __restrict__ X,   // (N, 256) f32
    const float* __restrict__ W,   // (256, 256) f32
    const float* __restrict__ G,   // (256,)
    float* __restrict__ out) {     // (N, 256) f32
  __shared__ __align__(16) unsigned char xs[BM * XSTR];   // 8.5 KB
  __shared__ __align__(16) unsigned char wsl[BN * XSTR];  // 8.5 KB

  const int tid = threadIdx.x;
  const int r0 = blockIdx.x * BM;
  const int c0 = blockIdx.y * BN;

  // stage + tanh + quantize both tiles: 32 rows x 64 float4-chunks each.
  // consecutive tids hit consecutive 16B global chunks (coalesced) and
  // consecutive LDS dwords (bank-cycling, conflict-free).
#pragma unroll
  for (int p = 0; p < 8; ++p) {
    int id  = tid + p * 256;        // 0..2047
    int row = id >> 6;
    int c4  = id & 63;
    float4 xv = *reinterpret_cast<const float4*>(&X[(size_t)(r0 + row) * DIN + c4 * 4]);
    *reinterpret_cast<unsigned*>(&xs[row * XSTR + c4 * 4]) = quant4(xv);
    float4 wv = *reinterpret_cast<const float4*>(&W[(size_t)(c0 + row) * DIN + c4 * 4]);
    *reinterpret_cast<unsigned*>(&wsl[row * XSTR + c4 * 4]) = quant4(wv);
  }
  __syncthreads();

  const int wave = tid >> 6;            // 2x2 wave grid of 16x16 sub-tiles
  const int wr = (wave >> 1) * 16;
  const int wc = (wave & 1) * 16;
  const int lane = tid & 63;
  const int tr = lane >> 3;             // 0..7  (x-rows tr, tr+8)
  const int tc = lane & 7;              // 0..7  (w-cols 2tc, 2tc+1)

  const unsigned char* xr0 = &xs[(wr + tr) * XSTR];
  const unsigned char* xr1 = xr0 + 8 * XSTR;
  const unsigned char* wc0 = &wsl[(wc + 2 * tc) * XSTR];
  const unsigned char* wc1 = wc0 + XSTR;

  unsigned a00 = 0, a01 = 0, a10 = 0, a11 = 0;
#pragma unroll
  for (int k = 0; k < 16; ++k) {
    uint4 xv0 = *reinterpret_cast<const uint4*>(xr0 + k * 16);
    uint4 xv1 = *reinterpret_cast<const uint4*>(xr1 + k * 16);
    uint4 wv0 = *reinterpret_cast<const uint4*>(wc0 + k * 16);
    uint4 wv1 = *reinterpret_cast<const uint4*>(wc1 + k * 16);
    a00 = sad_u8(xv0.x, wv0.x, a00); a01 = sad_u8(xv0.x, wv1.x, a01);
    a10 = sad_u8(xv1.x, wv0.x, a10); a11 = sad_u8(xv1.x, wv1.x, a11);
    a00 = sad_u8(xv0.y, wv0.y, a00); a01 = sad_u8(xv0.y, wv1.y, a01);
    a10 = sad_u8(xv1.y, wv0.y, a10); a11 = sad_u8(xv1.y, wv1.y, a11);
    a00 = sad_u8(xv0.z, wv0.z, a00); a01 = sad_u8(xv0.z, wv1.z, a01);
    a10 = sad_u8(xv1.z, wv0.z, a10); a11 = sad_u8(xv1.z, wv1.z, a11);
    a00 = sad_u8(xv0.w, wv0.w, a00); a01 = sad_u8(xv0.w, wv1.w, a01);
    a10 = sad_u8(xv1.w, wv0.w, a10); a11 = sad_u8(xv1.w, wv1.w, a11);
  }

  const float s = 1.0f / (127.5f * 256.0f);
  const int R0 = r0 + wr + tr;
  const int R1 = R0 + 8;
  const int C0 = c0 + wc + 2 * tc;
  const float g0 = G[C0], g1 = G[C0 + 1];
  float2 o0, o1;
  o0.x = (0.5f - a00 * s) * g0; o0.y = (0.5f - a01 * s) * g1;
  o1.x = (0.5f - a10 * s) * g0; o1.y = (0.5f - a11 * s) * g1;
  *reinterpret_cast<float2*>(&out[(size_t)R0 * 256 + C0]) = o0;
  *reinterpret_cast<float2*>(&out[(size_t)R1 * 256 + C0]) = o1;
}

// ---------------- fallback (shape misfit): fused f32 path ----------------
#define KT 128
#define STRIDE 132
#define TM 32
#define TN 32

__device__ __forceinline__ float4 tanh4(float4 v) {
  v.x = tanhf(v.x); v.y = tanhf(v.y); v.z = tanhf(v.z); v.w = tanhf(v.w);
  return v;
}

__global__ __launch_bounds__(256, 2) void l1_f32_fused_kernel(
    const float* __restrict__ X, const float* __restrict__ W,
    const float* __restrict__ G, float* __restrict__ out) {
  __shared__ float xs[TM * STRIDE];
  __shared__ float wsl[TN * STRIDE];
  const int tid = threadIdx.x;
  const int r0 = blockIdx.x * TM;
  const int c0 = blockIdx.y * TN;
  const int wave = tid >> 6;
  const int lane = tid & 63;
  const int lr = lane >> 4;
  const int lc = lane & 15;
  float acc[2][2] = {{0.f, 0.f}, {0.f, 0.f}};
  for (int kp = 0; kp < DIN; kp += KT) {
    __syncthreads();
    for (int it = tid; it < TM * (KT / 4); it += 256) {
      int r = it >> 5, c4 = it & 31;
      float4 v = *reinterpret_cast<const float4*>(X + (size_t)(r0 + r) * DIN + kp + c4 * 4);
      *reinterpret_cast<float4*>(&xs[r * STRIDE + c4 * 4]) = tanh4(v);
    }
    for (int it = tid; it < TN * (KT / 4); it += 256) {
      int r = it >> 5, c4 = it & 31;
      float4 v = *reinterpret_cast<const float4*>(W + (size_t)(c0 + r) * DIN + kp + c4 * 4);
      *reinterpret_cast<float4*>(&wsl[r * STRIDE + c4 * 4]) = tanh4(v);
    }
    __syncthreads();
    const float* xb = &xs[(8 * wave + lr) * STRIDE];
    const float* wb = &wsl[lc * STRIDE];
#pragma unroll
    for (int k = 0; k < KT; k += 4) {
      float4 x0 = *reinterpret_cast<const float4*>(xb + k);
      float4 x1 = *reinterpret_cast<const float4*>(xb + 4 * STRIDE + k);
      float4 w0 = *reinterpret_cast<const float4*>(wb + k);
      float4 w1 = *reinterpret_cast<const float4*>(wb + 16 * STRIDE + k);
      acc[0][0] += (fabsf(x0.x - w0.x) + fabsf(x0.y - w0.y)) + (fabsf(x0.z - w0.z) + fabsf(x0.w - w0.w));
      acc[0][1] += (fabsf(x0.x - w1.x) + fabsf(x0.y - w1.y)) + (fabsf(x0.z - w1.z) + fabsf(x0.w - w1.w));
      acc[1][0] += (fabsf(x1.x - w0.x) + fabsf(x1.y - w0.y)) + (fabsf(x1.z - w0.z) + fabsf(x1.w - w0.w));
      acc[1][1] += (fabsf(x1.x - w1.x) + fabsf(x1.y - w1.y)) + (fabsf(x1.z - w1.z) + fabsf(x1.w - w1.w));
    }
  }
  const float inv = 1.0f / DIN;
#pragma unroll
  for (int j = 0; j < 2; ++j) {
    int C = c0 + lc + 16 * j;
    float g = G[C];
#pragma unroll
    for (int i = 0; i < 2; ++i) {
      int R = r0 + 8 * wave + lr + 4 * i;
      out[(size_t)R * 256 + C] = (0.5f - acc[i][j] * inv) * g;
    }
  }
}

extern "C" void kernel_launch(void* const* d_in, const int* in_sizes, int n_in,
                              void* d_out, int out_size, void* d_ws, size_t ws_size,
                              hipStream_t stream) {
  const float* x = (const float*)d_in[0];   // (2,1024,256) f32
  const float* w = (const float*)d_in[1];   // (256,256) f32
  const float* g = (const float*)d_in[2];   // (1,256,1) f32
  float* out = (float*)d_out;

  const int N = in_sizes[0] / DIN;          // 2048
  const int Dout = 256;

  if ((N % BM) == 0) {
    dim3 grid(N / BM, Dout / BN);           // (64, 8) = 512 blocks
    fused_sad_kernel<<<grid, 256, 0, stream>>>(x, w, g, out);
  } else {
    dim3 grid((N + TM - 1) / TM, Dout / TN);
    l1_f32_fused_kernel<<<grid, 256, 0, stream>>>(x, w, g, out);
  }
}

// Round 6
// 10.993 us; speedup vs baseline: 2.0323x; 1.1504x over previous
//
#include <hip/hip_runtime.h>
#include <math.h>

// out[n,d] = (0.5 - (1/256) * sum_k |tanh(x[n,k]) - tanh(w[d,k])|) * gain[d]
// Straight-through estimator: forward value is the L1 branch only.
//
// Round-6: single fused kernel (launch floor ~10us dominates; kernel ~1.8us).
// Trim the staging math: q_u8 = round(255*(tanh(x)+1)/2) computed as
//   e = exp2(x * 2*log2e);  r = rcp(e+1);  q = fma(-255, r, 255.5)
// -> 4 VALU + 2 trans per element, no clamp (inf/0 handled by rcp), and
// byte-packing via v_cvt_pk_u8_f32. SAD loop unchanged: v_sad_u8 = 4 |a-b|
// + accumulate per VALU op, 8-way broadcast LDS reads, one barrier.

#define DIN 256
#define BM 32
#define BN 32
#define XSTR 272   // LDS row stride in bytes (256 + 16)

__device__ __forceinline__ unsigned sad_u8(unsigned a, unsigned b, unsigned acc) {
#if __has_builtin(__builtin_amdgcn_sad_u8)
  return __builtin_amdgcn_sad_u8(a, b, acc);
#else
  unsigned d;
  asm("v_sad_u8 %0, %1, %2, %3" : "=v"(d) : "v"(a), "v"(b), "v"(acc));
  return d;
#endif
}

__device__ __forceinline__ float rcp_f(float v) {
#if __has_builtin(__builtin_amdgcn_rcpf)
  return __builtin_amdgcn_rcpf(v);
#else
  return 1.0f / v;
#endif
}

// q = round_half_up(255 * (tanh(x)+1)/2), branch/clamp-free
__device__ __forceinline__ float quant1(float x) {
  float e = exp2f(x * 2.8853900817779268f);   // e^(2x) via v_exp_f32
  float r = rcp_f(e + 1.0f);                  // x->+inf: 0, x->-inf: 1
  return fmaf(-255.0f, r, 255.5f);            // in [0.5, 255.5]
}

__device__ __forceinline__ unsigned quant4(float4 v) {
  float q0 = quant1(v.x), q1 = quant1(v.y), q2 = quant1(v.z), q3 = quant1(v.w);
#if __has_builtin(__builtin_amdgcn_cvt_pk_u8_f32)
  unsigned p = 0;
  p = __builtin_amdgcn_cvt_pk_u8_f32(q0, 0, p);
  p = __builtin_amdgcn_cvt_pk_u8_f32(q1, 1, p);
  p = __builtin_amdgcn_cvt_pk_u8_f32(q2, 2, p);
  p = __builtin_amdgcn_cvt_pk_u8_f32(q3, 3, p);
  return p;
#else
  return (unsigned)q0 | ((unsigned)q1 << 8) | ((unsigned)q2 << 16) | ((unsigned)q3 << 24);
#endif
}

__global__ __launch_bounds__(256) void fused_sad_kernel(
    const float* __restrict__ X,   // (N, 256) f32
    const float* __restrict__ W,   // (256, 256) f32
    const float* __restrict__ G,   // (256,)
    float* __restrict__ out) {     // (N, 256) f32
  __shared__ __align__(16) unsigned char xs[BM * XSTR];   // 8.5 KB
  __shared__ __align__(16) unsigned char wsl[BN * XSTR];  // 8.5 KB

  const int tid = threadIdx.x;
  const int r0 = blockIdx.x * BM;
  const int c0 = blockIdx.y * BN;

  // stage + tanh + quantize both tiles: 32 rows x 64 float4-chunks each.
#pragma unroll
  for (int p = 0; p < 8; ++p) {
    int id  = tid + p * 256;        // 0..2047
    int row = id >> 6;
    int c4  = id & 63;
    float4 xv = *reinterpret_cast<const float4*>(&X[(size_t)(r0 + row) * DIN + c4 * 4]);
    *reinterpret_cast<unsigned*>(&xs[row * XSTR + c4 * 4]) = quant4(xv);
    float4 wv = *reinterpret_cast<const float4*>(&W[(size_t)(c0 + row) * DIN + c4 * 4]);
    *reinterpret_cast<unsigned*>(&wsl[row * XSTR + c4 * 4]) = quant4(wv);
  }
  __syncthreads();

  const int wave = tid >> 6;            // 2x2 wave grid of 16x16 sub-tiles
  const int wr = (wave >> 1) * 16;
  const int wc = (wave & 1) * 16;
  const int lane = tid & 63;
  const int tr = lane >> 3;             // 0..7  (x-rows tr, tr+8)
  const int tc = lane & 7;              // 0..7  (w-cols 2tc, 2tc+1)

  const unsigned char* xr0 = &xs[(wr + tr) * XSTR];
  const unsigned char* xr1 = xr0 + 8 * XSTR;
  const unsigned char* wc0 = &wsl[(wc + 2 * tc) * XSTR];
  const unsigned char* wc1 = wc0 + XSTR;

  unsigned a00 = 0, a01 = 0, a10 = 0, a11 = 0;
#pragma unroll
  for (int k = 0; k < 16; ++k) {
    uint4 xv0 = *reinterpret_cast<const uint4*>(xr0 + k * 16);
    uint4 xv1 = *reinterpret_cast<const uint4*>(xr1 + k * 16);
    uint4 wv0 = *reinterpret_cast<const uint4*>(wc0 + k * 16);
    uint4 wv1 = *reinterpret_cast<const uint4*>(wc1 + k * 16);
    a00 = sad_u8(xv0.x, wv0.x, a00); a01 = sad_u8(xv0.x, wv1.x, a01);
    a10 = sad_u8(xv1.x, wv0.x, a10); a11 = sad_u8(xv1.x, wv1.x, a11);
    a00 = sad_u8(xv0.y, wv0.y, a00); a01 = sad_u8(xv0.y, wv1.y, a01);
    a10 = sad_u8(xv1.y, wv0.y, a10); a11 = sad_u8(xv1.y, wv1.y, a11);
    a00 = sad_u8(xv0.z, wv0.z, a00); a01 = sad_u8(xv0.z, wv1.z, a01);
    a10 = sad_u8(xv1.z, wv0.z, a10); a11 = sad_u8(xv1.z, wv1.z, a11);
    a00 = sad_u8(xv0.w, wv0.w, a00); a01 = sad_u8(xv0.w, wv1.w, a01);
    a10 = sad_u8(xv1.w, wv0.w, a10); a11 = sad_u8(xv1.w, wv1.w, a11);
  }

  const float s = 1.0f / (127.5f * 256.0f);
  const int R0 = r0 + wr + tr;
  const int R1 = R0 + 8;
  const int C0 = c0 + wc + 2 * tc;
  const float g0 = G[C0], g1 = G[C0 + 1];
  float2 o0, o1;
  o0.x = (0.5f - a00 * s) * g0; o0.y = (0.5f - a01 * s) * g1;
  o1.x = (0.5f - a10 * s) * g0; o1.y = (0.5f - a11 * s) * g1;
  *reinterpret_cast<float2*>(&out[(size_t)R0 * 256 + C0]) = o0;
  *reinterpret_cast<float2*>(&out[(size_t)R1 * 256 + C0]) = o1;
}

// ---------------- fallback (shape misfit): fused f32 path ----------------
#define KT 128
#define STRIDE 132
#define TM 32
#define TN 32

__device__ __forceinline__ float4 tanh4(float4 v) {
  v.x = tanhf(v.x); v.y = tanhf(v.y); v.z = tanhf(v.z); v.w = tanhf(v.w);
  return v;
}

__global__ __launch_bounds__(256, 2) void l1_f32_fused_kernel(
    const float* __restrict__ X, const float* __restrict__ W,
    const float* __restrict__ G, float* __restrict__ out) {
  __shared__ float xs[TM * STRIDE];
  __shared__ float wsl[TN * STRIDE];
  const int tid = threadIdx.x;
  const int r0 = blockIdx.x * TM;
  const int c0 = blockIdx.y * TN;
  const int wave = tid >> 6;
  const int lane = tid & 63;
  const int lr = lane >> 4;
  const int lc = lane & 15;
  float acc[2][2] = {{0.f, 0.f}, {0.f, 0.f}};
  for (int kp = 0; kp < DIN; kp += KT) {
    __syncthreads();
    for (int it = tid; it < TM * (KT / 4); it += 256) {
      int r = it >> 5, c4 = it & 31;
      float4 v = *reinterpret_cast<const float4*>(X + (size_t)(r0 + r) * DIN + kp + c4 * 4);
      *reinterpret_cast<float4*>(&xs[r * STRIDE + c4 * 4]) = tanh4(v);
    }
    for (int it = tid; it < TN * (KT / 4); it += 256) {
      int r = it >> 5, c4 = it & 31;
      float4 v = *reinterpret_cast<const float4*>(W + (size_t)(c0 + r) * DIN + kp + c4 * 4);
      *reinterpret_cast<float4*>(&wsl[r * STRIDE + c4 * 4]) = tanh4(v);
    }
    __syncthreads();
    const float* xb = &xs[(8 * wave + lr) * STRIDE];
    const float* wb = &wsl[lc * STRIDE];
#pragma unroll
    for (int k = 0; k < KT; k += 4) {
      float4 x0 = *reinterpret_cast<const float4*>(xb + k);
      float4 x1 = *reinterpret_cast<const float4*>(xb + 4 * STRIDE + k);
      float4 w0 = *reinterpret_cast<const float4*>(wb + k);
      float4 w1 = *reinterpret_cast<const float4*>(wb + 16 * STRIDE + k);
      acc[0][0] += (fabsf(x0.x - w0.x) + fabsf(x0.y - w0.y)) + (fabsf(x0.z - w0.z) + fabsf(x0.w - w0.w));
      acc[0][1] += (fabsf(x0.x - w1.x) + fabsf(x0.y - w1.y)) + (fabsf(x0.z - w1.z) + fabsf(x0.w - w1.w));
      acc[1][0] += (fabsf(x1.x - w0.x) + fabsf(x1.y - w0.y)) + (fabsf(x1.z - w0.z) + fabsf(x1.w - w0.w));
      acc[1][1] += (fabsf(x1.x - w1.x) + fabsf(x1.y - w1.y)) + (fabsf(x1.z - w1.z) + fabsf(x1.w - w1.w));
    }
  }
  const float inv = 1.0f / DIN;
#pragma unroll
  for (int j = 0; j < 2; ++j) {
    int C = c0 + lc + 16 * j;
    float g = G[C];
#pragma unroll
    for (int i = 0; i < 2; ++i) {
      int R = r0 + 8 * wave + lr + 4 * i;
      out[(size_t)R * 256 + C] = (0.5f - acc[i][j] * inv) * g;
    }
  }
}

extern "C" void kernel_launch(void* const* d_in, const int* in_sizes, int n_in,
                              void* d_out, int out_size, void* d_ws, size_t ws_size,
                              hipStream_t stream) {
  const float* x = (const float*)d_in[0];   // (2,1024,256) f32
  const float* w = (const float*)d_in[1];   // (256,256) f32
  const float* g = (const float*)d_in[2];   // (1,256,1) f32
  float* out = (float*)d_out;

  const int N = in_sizes[0] / DIN;          // 2048
  const int Dout = 256;

  if ((N % BM) == 0) {
    dim3 grid(N / BM, Dout / BN);           // (64, 8) = 512 blocks
    fused_sad_kernel<<<grid, 256, 0, stream>>>(x, w, g, out);
  } else {
    dim3 grid((N + TM - 1) / TM, Dout / TN);
    l1_f32_fused_kernel<<<grid, 256, 0, stream>>>(x, w, g, out);
  }
}